// Round 12
// baseline (212.867 us; speedup 1.0000x reference)
//
#include <hip/hip_runtime.h>
#include <hip/hip_bf16.h>

// GAT encoder, 2 layers. B=32, N=512, D=64, H=8, DK=8.
// Layer: xp = x@W -> s,t per head -> masked softmax over sources i per target j
//        -> out[j,h,:] = sum_i alpha * xp[i,h,:]  -> +bias, relu.
//
// Design ledger:
//  - Softmax shift m[j,h] = lrelu(smax[b,h] + t[j,h]) is a FIXED upper bound
//    (leaky_relu monotone) -> single pass over i, exp arg <= 0. (R2, verified)
//  - R6: global f32 atomicAdd dense combine = 133 MB HBM RMW. Never again.
//  - R9/R10: barrier-lockstep LDS pipeline invariant ~50 us regardless of DS
//    count or conflicts (VALUBusy 55%, Occ 35%): waves park at vmcnt(0)+barrier
//    while adj (HBM, ~900cy) lands; compute phase (~300cy) can't cover it.
//  - R10 swizzle was wrong: 4.06M bank conflicts. Lesson: verify swizzle algebra
//    against bank = (addr/4)%32 for the actual lane map before shipping.
//  - R11 (this): aggr barrier-free. 8 independent waves each own 64 sources,
//    direct L1/L2 loads (xp is 4MB, L2-resident; don't LDS-stage what caches
//    fit). One final LDS reduce. proj UNTOUCHED (3 blind redesigns all ~40us;
//    waiting for it to surface in top-5 for real counters).

namespace {

constexpr int NB = 32;      // batch
constexpr int NN = 512;     // nodes

__device__ __forceinline__ float lrelu(float x) { return fmaxf(x, 0.2f * x); }

// ---------------- Kernel A: xp = x@W ; s,t ; per-block s-max -> pmax --------
// grid: (B*N/16) = 1024 blocks, 256 threads. Thread (r=tid>>4, c4=tid&15)
// computes cols c4*4..c4*4+3 of its row.  [UNCHANGED from R10]
__global__ __launch_bounds__(256) void gat_proj(
    const float* __restrict__ x,     // [B*N, 64]
    const float* __restrict__ W,     // [64, 64]
    const float* __restrict__ asrc,  // [8, 8]
    const float* __restrict__ adst,  // [8, 8]
    float* __restrict__ xp,          // [B*N, 64]
    float* __restrict__ s,           // [B*N, 8]
    float* __restrict__ t,           // [B*N, 8]
    float* __restrict__ pmax)        // [1024, 8] per-block s-max (dense)
{
    __shared__ float Wl[64 * 64];    // 16 KB
    __shared__ float xs[16 * 68];    // padded rows (68 = 17 float4) 4.25 KB
    __shared__ float red[16 * 8];
    const int tid = threadIdx.x;
    const int row0 = blockIdx.x * 16;

    float4 wreg[4];
    const float4* W4 = reinterpret_cast<const float4*>(W);
    #pragma unroll
    for (int it = 0; it < 4; ++it) wreg[it] = W4[it * 256 + tid];
    const float4 xreg = reinterpret_cast<const float4*>(&x[row0 * 64])[tid];

    float4* Wl4 = reinterpret_cast<float4*>(Wl);
    #pragma unroll
    for (int it = 0; it < 4; ++it) Wl4[it * 256 + tid] = wreg[it];
    reinterpret_cast<float4*>(xs)[(tid >> 4) * 17 + (tid & 15)] = xreg;
    __syncthreads();

    const int r = tid >> 4;
    const int c4 = tid & 15;
    const int c0 = c4 * 4;
    const int h = c4 >> 1, half = c4 & 1;

    float acc[4] = {};
    #pragma unroll 4
    for (int k = 0; k < 64; ++k) {
        const float xv = xs[r * 68 + k];
        const float4 w4 = *reinterpret_cast<const float4*>(&Wl[k * 64 + c0]);
        acc[0] = fmaf(xv, w4.x, acc[0]);
        acc[1] = fmaf(xv, w4.y, acc[1]);
        acc[2] = fmaf(xv, w4.z, acc[2]);
        acc[3] = fmaf(xv, w4.w, acc[3]);
    }
    const int row = row0 + r;
    *reinterpret_cast<float4*>(&xp[row * 64 + c0]) =
        make_float4(acc[0], acc[1], acc[2], acc[3]);

    const float4 a4 = *reinterpret_cast<const float4*>(&asrc[h * 8 + half * 4]);
    const float4 d4 = *reinterpret_cast<const float4*>(&adst[h * 8 + half * 4]);
    float sp = acc[0] * a4.x + acc[1] * a4.y + acc[2] * a4.z + acc[3] * a4.w;
    float tp = acc[0] * d4.x + acc[1] * d4.y + acc[2] * d4.z + acc[3] * d4.w;
    sp += __shfl_xor(sp, 1);
    tp += __shfl_xor(tp, 1);
    if (half == 0) {
        s[row * 8 + h] = sp;
        t[row * 8 + h] = tp;
        red[r * 8 + h] = sp;
    }
    __syncthreads();
    if (tid < 8) {
        float mx = red[tid];
        #pragma unroll
        for (int rr = 1; rr < 16; ++rr) mx = fmaxf(mx, red[rr * 8 + tid]);
        pmax[blockIdx.x * 8 + tid] = mx;
    }
}

// ---------------- Kernel B: masked softmax over i + aggregation -------------
// grid: (N/16, B) = 1024 blocks, 512 threads = 8 INDEPENDENT waves.
// Wave w owns sources i in [64w, 64w+64); lane = (jp=lane>>3, h=lane&7) owns
// targets j0+jp*2, j0+jp*2+1. Direct global loads (no LDS staging, no
// main-loop barriers). Final: one LDS reduce over the 8 wave-partials.
__global__ __launch_bounds__(512) void gat_aggr(
    const float* __restrict__ xp,    // [B*N, 64]
    const float* __restrict__ s,     // [B*N, 8]
    const float* __restrict__ t,     // [B*N, 8]
    const float* __restrict__ pmax,  // [1024, 8] = [B][32][8]
    const int*   __restrict__ adj,   // [B, N, N]
    const float* __restrict__ bias,  // [64]
    float* __restrict__ outp)        // [B*N, 64]
{
    __shared__ float red[8 * 128 * 9];  // [wave][combo][acc8+l], 36.9 KB

    const int tid = threadIdx.x;
    const int b = blockIdx.y;
    const int j0 = blockIdx.x * 16;
    const int wid = tid >> 6;
    const int lane = tid & 63;
    const int h  = lane & 7;
    const int jp = lane >> 3;          // 0..7
    const int j_0 = j0 + jp * 2;
    const int j_1 = j_0 + 1;

    // smax[b,h]: max over the 32 proj-block maxima (L1-broadcast loads)
    float sm = pmax[(b * 32) * 8 + h];
    #pragma unroll
    for (int q = 1; q < 32; ++q) sm = fmaxf(sm, pmax[(b * 32 + q) * 8 + h]);

    const float tv0 = t[(b * NN + j_0) * 8 + h];
    const float tv1 = t[(b * NN + j_1) * 8 + h];
    const float m0 = lrelu(sm + tv0);  // >= all e for (j_0,h)
    const float m1 = lrelu(sm + tv1);

    float acc0[8] = {}, acc1[8] = {};
    float l0 = 0.f, l1 = 0.f;

    const int ibase = wid * 64;
    const float* xr = xp + ((size_t)(b * NN + ibase)) * 64 + h * 8;
    const float* sr = s + ((size_t)(b * NN + ibase)) * 8 + h;
    const int*   ar = adj + ((size_t)(b * NN + ibase)) * NN + j0 + jp * 2;

    int i = ibase;
    for (int c = 0; c < 32; ++c) {    // 2 sources per iteration
        const float4 xa0 = *reinterpret_cast<const float4*>(xr);
        const float4 xb0 = *reinterpret_cast<const float4*>(xr + 4);
        const float4 xa1 = *reinterpret_cast<const float4*>(xr + 64);
        const float4 xb1 = *reinterpret_cast<const float4*>(xr + 68);
        const int2  am0 = *reinterpret_cast<const int2*>(ar);
        const int2  am1 = *reinterpret_cast<const int2*>(ar + NN);
        const float sv0 = sr[0];
        const float sv1 = sr[8];
        xr += 128; sr += 16; ar += 2 * NN;

        {   // source i
            const float mk0 = (am0.x != 0 || i == j_0) ? 1.0f : 0.0f;
            const float mk1 = (am0.y != 0 || i == j_1) ? 1.0f : 0.0f;
            float z = sv0 + tv0, e = fmaxf(z, 0.2f * z);
            const float p0 = mk0 * __expf(e - m0);
            z = sv0 + tv1; e = fmaxf(z, 0.2f * z);
            const float p1 = mk1 * __expf(e - m1);
            l0 += p0; l1 += p1;
            acc0[0] = fmaf(p0, xa0.x, acc0[0]); acc1[0] = fmaf(p1, xa0.x, acc1[0]);
            acc0[1] = fmaf(p0, xa0.y, acc0[1]); acc1[1] = fmaf(p1, xa0.y, acc1[1]);
            acc0[2] = fmaf(p0, xa0.z, acc0[2]); acc1[2] = fmaf(p1, xa0.z, acc1[2]);
            acc0[3] = fmaf(p0, xa0.w, acc0[3]); acc1[3] = fmaf(p1, xa0.w, acc1[3]);
            acc0[4] = fmaf(p0, xb0.x, acc0[4]); acc1[4] = fmaf(p1, xb0.x, acc1[4]);
            acc0[5] = fmaf(p0, xb0.y, acc0[5]); acc1[5] = fmaf(p1, xb0.y, acc1[5]);
            acc0[6] = fmaf(p0, xb0.z, acc0[6]); acc1[6] = fmaf(p1, xb0.z, acc1[6]);
            acc0[7] = fmaf(p0, xb0.w, acc0[7]); acc1[7] = fmaf(p1, xb0.w, acc1[7]);
        }
        {   // source i+1
            const float mk0 = (am1.x != 0 || (i + 1) == j_0) ? 1.0f : 0.0f;
            const float mk1 = (am1.y != 0 || (i + 1) == j_1) ? 1.0f : 0.0f;
            float z = sv1 + tv0, e = fmaxf(z, 0.2f * z);
            const float p0 = mk0 * __expf(e - m0);
            z = sv1 + tv1; e = fmaxf(z, 0.2f * z);
            const float p1 = mk1 * __expf(e - m1);
            l0 += p0; l1 += p1;
            acc0[0] = fmaf(p0, xa1.x, acc0[0]); acc1[0] = fmaf(p1, xa1.x, acc1[0]);
            acc0[1] = fmaf(p0, xa1.y, acc0[1]); acc1[1] = fmaf(p1, xa1.y, acc1[1]);
            acc0[2] = fmaf(p0, xa1.z, acc0[2]); acc1[2] = fmaf(p1, xa1.z, acc1[2]);
            acc0[3] = fmaf(p0, xa1.w, acc0[3]); acc1[3] = fmaf(p1, xa1.w, acc1[3]);
            acc0[4] = fmaf(p0, xb1.x, acc0[4]); acc1[4] = fmaf(p1, xb1.x, acc1[4]);
            acc0[5] = fmaf(p0, xb1.y, acc0[5]); acc1[5] = fmaf(p1, xb1.y, acc1[5]);
            acc0[6] = fmaf(p0, xb1.z, acc0[6]); acc1[6] = fmaf(p1, xb1.z, acc1[6]);
            acc0[7] = fmaf(p0, xb1.w, acc0[7]); acc1[7] = fmaf(p1, xb1.w, acc1[7]);
        }
        i += 2;
    }

    // write wave-partials: combo = jj*8 + h; stride 9 (x9 mod 32 bijective
    // per 32 combos -> 2 lanes/bank max = free)
    {
        float* rb0 = &red[(wid * 128 + (jp * 2 + 0) * 8 + h) * 9];
        float* rb1 = &red[(wid * 128 + (jp * 2 + 1) * 8 + h) * 9];
        #pragma unroll
        for (int d = 0; d < 8; ++d) { rb0[d] = acc0[d]; rb1[d] = acc1[d]; }
        rb0[8] = l0; rb1[8] = l1;
    }
    __syncthreads();

    if (tid < 128) {                  // combo = jj*8 + h
        float o[9];
        #pragma unroll
        for (int d = 0; d < 9; ++d) o[d] = red[tid * 9 + d];
        #pragma unroll
        for (int w = 1; w < 8; ++w)
            #pragma unroll
            for (int d = 0; d < 9; ++d) o[d] += red[(w * 128 + tid) * 9 + d];

        const int hh = tid & 7;
        const float rec = 1.0f / o[8];
        const float4 b0 = *reinterpret_cast<const float4*>(&bias[hh * 8]);
        const float4 b1 = *reinterpret_cast<const float4*>(&bias[hh * 8 + 4]);
        float4 o0, o1;
        o0.x = fmaxf(fmaf(o[0], rec, b0.x), 0.0f);
        o0.y = fmaxf(fmaf(o[1], rec, b0.y), 0.0f);
        o0.z = fmaxf(fmaf(o[2], rec, b0.z), 0.0f);
        o0.w = fmaxf(fmaf(o[3], rec, b0.w), 0.0f);
        o1.x = fmaxf(fmaf(o[4], rec, b1.x), 0.0f);
        o1.y = fmaxf(fmaf(o[5], rec, b1.y), 0.0f);
        o1.z = fmaxf(fmaf(o[6], rec, b1.z), 0.0f);
        o1.w = fmaxf(fmaf(o[7], rec, b1.w), 0.0f);
        const int row = b * NN + j0 + (tid >> 3);
        float4* po = reinterpret_cast<float4*>(&outp[row * 64 + hh * 8]);
        po[0] = o0;
        po[1] = o1;
    }
}

} // namespace

extern "C" void kernel_launch(void* const* d_in, const int* in_sizes, int n_in,
                              void* d_out, int out_size, void* d_ws, size_t ws_size,
                              hipStream_t stream) {
    const float* n_in0  = (const float*)d_in[0];   // [B,N,64]
    const int*   adj    = (const int*)d_in[1];     // [B,N,N]
    const float* W1     = (const float*)d_in[2];
    const float* asrc1  = (const float*)d_in[3];
    const float* adst1  = (const float*)d_in[4];
    const float* b1     = (const float*)d_in[5];
    const float* W2     = (const float*)d_in[6];
    const float* asrc2  = (const float*)d_in[7];
    const float* adst2  = (const float*)d_in[8];
    const float* b2     = (const float*)d_in[9];

    float* ws = (float*)d_ws;
    float* xp   = ws;                    // 1048576 floats
    float* s    = xp + 1048576;          // 131072
    float* t    = s + 131072;            // 131072
    float* x2   = t + 131072;            // 1048576
    float* pmax = x2 + 1048576;          // 8192 (dense-written every call)

    const dim3 gProj(NB * NN / 16);      // 1024 blocks x 16 rows
    const dim3 gAggr(NN / 16, NB);       // 1024 blocks

    // Layer 1
    gat_proj<<<gProj, 256, 0, stream>>>(n_in0, W1, asrc1, adst1, xp, s, t, pmax);
    gat_aggr<<<gAggr, 512, 0, stream>>>(xp, s, t, pmax, adj, b1, x2);
    // Layer 2
    gat_proj<<<gProj, 256, 0, stream>>>(x2, W2, asrc2, adst2, xp, s, t, pmax);
    gat_aggr<<<gAggr, 512, 0, stream>>>(xp, s, t, pmax, adj, b2, (float*)d_out);
}

// Round 13
// 175.048 us; speedup vs baseline: 1.2160x; 1.2160x over previous
//
#include <hip/hip_runtime.h>
#include <hip/hip_bf16.h>

// GAT encoder, 2 layers. B=32, N=512, D=64, H=8, DK=8.
// Layer: xp = x@W -> s,t per head -> masked softmax over sources i per target j
//        -> out[j,h,:] = sum_i alpha * xp[i,h,:]  -> +bias, relu.
//
// Design ledger:
//  - Softmax shift m[j,h] = lrelu(smax[b,h] + t[j,h]) is a FIXED upper bound
//    (leaky_relu monotone) -> single pass over i, exp arg <= 0. (R2, verified)
//  - R6: global f32 atomicAdd dense combine = 133 MB HBM RMW. Never again.
//  - R10: swizzle algebra was wrong (4M conflicts). R11/R12: barrier-free
//    direct-load aggr REGRESSED (70 us, VALUBusy 39%): 4x VMEM issues, no
//    pipelining. R9 LDS-staged aggr = best measured (48 us, busy-time ~26us).
//  - ~80 us/run lives OUTSIDE aggr (2x proj ~40 us by subtraction, stable
//    across 3 proj structures; no counters ever captured).
//  - R13 (this): aggr reverted to R9 exactly; layer-2 proj FUSED into layer-1
//    aggr epilogue (out rows -> LDS -> x2@W2 in-block; W2 prefetched).
//    Deletes 1 dispatch + x2 round-trip. Decisive: total -40us => proj real;
//    total flat => remainder is fixed overhead, aggr-only levers next.

namespace {

constexpr int NB = 32;      // batch
constexpr int NN = 512;     // nodes

__device__ __forceinline__ float lrelu(float x) { return fmaxf(x, 0.2f * x); }

// ---------------- Kernel 1: xp1 = x@W1 ; s1,t1 ; pmax1 ----------------------
// grid: (B*N/16) = 1024 blocks, 256 threads. [UNCHANGED 4th round]
__global__ __launch_bounds__(256) void gat_proj(
    const float* __restrict__ x,     // [B*N, 64]
    const float* __restrict__ W,     // [64, 64]
    const float* __restrict__ asrc,  // [8, 8]
    const float* __restrict__ adst,  // [8, 8]
    float* __restrict__ xp,          // [B*N, 64]
    float* __restrict__ s,           // [B*N, 8]
    float* __restrict__ t,           // [B*N, 8]
    float* __restrict__ pmax)        // [1024, 8]
{
    __shared__ float Wl[64 * 64];
    __shared__ float xs[16 * 68];
    __shared__ float red[16 * 8];
    const int tid = threadIdx.x;
    const int row0 = blockIdx.x * 16;

    float4 wreg[4];
    const float4* W4 = reinterpret_cast<const float4*>(W);
    #pragma unroll
    for (int it = 0; it < 4; ++it) wreg[it] = W4[it * 256 + tid];
    const float4 xreg = reinterpret_cast<const float4*>(&x[row0 * 64])[tid];

    float4* Wl4 = reinterpret_cast<float4*>(Wl);
    #pragma unroll
    for (int it = 0; it < 4; ++it) Wl4[it * 256 + tid] = wreg[it];
    reinterpret_cast<float4*>(xs)[(tid >> 4) * 17 + (tid & 15)] = xreg;
    __syncthreads();

    const int r = tid >> 4;
    const int c4 = tid & 15;
    const int c0 = c4 * 4;
    const int h = c4 >> 1, half = c4 & 1;

    float acc[4] = {};
    #pragma unroll 4
    for (int k = 0; k < 64; ++k) {
        const float xv = xs[r * 68 + k];
        const float4 w4 = *reinterpret_cast<const float4*>(&Wl[k * 64 + c0]);
        acc[0] = fmaf(xv, w4.x, acc[0]);
        acc[1] = fmaf(xv, w4.y, acc[1]);
        acc[2] = fmaf(xv, w4.z, acc[2]);
        acc[3] = fmaf(xv, w4.w, acc[3]);
    }
    const int row = row0 + r;
    *reinterpret_cast<float4*>(&xp[row * 64 + c0]) =
        make_float4(acc[0], acc[1], acc[2], acc[3]);

    const float4 a4 = *reinterpret_cast<const float4*>(&asrc[h * 8 + half * 4]);
    const float4 d4 = *reinterpret_cast<const float4*>(&adst[h * 8 + half * 4]);
    float sp = acc[0] * a4.x + acc[1] * a4.y + acc[2] * a4.z + acc[3] * a4.w;
    float tp = acc[0] * d4.x + acc[1] * d4.y + acc[2] * d4.z + acc[3] * d4.w;
    sp += __shfl_xor(sp, 1);
    tp += __shfl_xor(tp, 1);
    if (half == 0) {
        s[row * 8 + h] = sp;
        t[row * 8 + h] = tp;
        red[r * 8 + h] = sp;
    }
    __syncthreads();
    if (tid < 8) {
        float mx = red[tid];
        #pragma unroll
        for (int rr = 1; rr < 16; ++rr) mx = fmaxf(mx, red[rr * 8 + tid]);
        pmax[blockIdx.x * 8 + tid] = mx;
    }
}

// ---------------- Kernel 2: FUSED aggr(layer1) + proj(layer2) ---------------
// grid: (N/16, B) = 1024 blocks, 512 threads. R9 aggr core (iq4 x jj16 x h8,
// LDS-staged chunks, reg prefetch), then: out rows -> xs2 LDS -> x2@W2 ->
// xp2, s2, t2, pmax2. W2 prefetched at kernel start into dedicated LDS.
__global__ __launch_bounds__(512) void gat_mid(
    const float* __restrict__ xp,    // [B*N, 64]  layer-1 xp
    const float* __restrict__ s,     // [B*N, 8]
    const float* __restrict__ t,     // [B*N, 8]
    const float* __restrict__ pmax,  // [1024, 8] = [B][32][8]
    const int*   __restrict__ adj,   // [B, N, N]
    const float* __restrict__ bias,  // [64]      layer-1 bias
    const float* __restrict__ W2,    // [64, 64]
    const float* __restrict__ asrc2, // [8, 8]
    const float* __restrict__ adst2, // [8, 8]
    float* __restrict__ xp2,         // [B*N, 64]
    float* __restrict__ s2,          // [B*N, 8]
    float* __restrict__ t2,          // [B*N, 8]
    float* __restrict__ pmax2)       // [1024, 8]
{
    __shared__ float xpl[32 * 64];     // 8 KB
    __shared__ float sl[32 * 8];       // 1 KB (reused as s2-partial store later)
    __shared__ float ml[32 * 16];      // 2 KB
    __shared__ float red[4 * 128 * 9]; // 18 KB
    __shared__ float Wl2[64 * 64];     // 16 KB
    __shared__ float xs2[16 * 68];     // 4.25 KB

    const int tid = threadIdx.x;
    const int b = blockIdx.y;
    const int j0 = blockIdx.x * 16;
    const int iq = tid >> 7;
    const int jj = (tid >> 3) & 15;
    const int h  = tid & 7;
    const int j  = j0 + jj;

    // W2 prefetch (latency hides under everything below)
    const float4* W24 = reinterpret_cast<const float4*>(W2);
    const float4 w2a = W24[tid];
    const float4 w2b = W24[tid + 512];

    float sm = pmax[b * 256 + h];
    #pragma unroll
    for (int q = 1; q < 32; ++q) sm = fmaxf(sm, pmax[b * 256 + q * 8 + h]);

    const float tv = t[(b * NN + j) * 8 + h];
    const float m = lrelu(sm + tv);

    float acc[8] = {};
    float l = 0.f;

    float4 pa; float ps; int pmv;
    auto issue = [&](int i0) {
        pa = reinterpret_cast<const float4*>(&xp[(b * NN + i0) * 64])[tid];
        if (tid < 256) ps = s[(b * NN + i0) * 8 + tid];
        pmv = adj[(b * NN + i0 + (tid >> 4)) * NN + j0 + (tid & 15)];
    };
    issue(0);

    // commit W2 to LDS (waits only on the W2 loads; visible after next barrier)
    float4* Wl24 = reinterpret_cast<float4*>(Wl2);
    Wl24[tid] = w2a;
    Wl24[tid + 512] = w2b;

    for (int c = 0; c < NN / 32; ++c) {
        const int i0 = c * 32;
        __syncthreads();
        reinterpret_cast<float4*>(xpl)[tid] = pa;
        if (tid < 256) sl[tid] = ps;
        ml[tid] = (pmv != 0 || (i0 + (tid >> 4)) == (j0 + (tid & 15))) ? 1.0f : 0.0f;
        if (c + 1 < NN / 32) issue(i0 + 32);
        __syncthreads();

        #pragma unroll
        for (int u = 0; u < 8; ++u) {
            const int ii = iq * 8 + u;
            const float e = lrelu(sl[ii * 8 + h] + tv);
            const float p = ml[ii * 16 + jj] * __expf(e - m);
            l += p;
            const float4* xr = reinterpret_cast<const float4*>(&xpl[ii * 64 + h * 8]);
            const float4 xa = xr[0], xb = xr[1];
            acc[0] = fmaf(p, xa.x, acc[0]);
            acc[1] = fmaf(p, xa.y, acc[1]);
            acc[2] = fmaf(p, xa.z, acc[2]);
            acc[3] = fmaf(p, xa.w, acc[3]);
            acc[4] = fmaf(p, xb.x, acc[4]);
            acc[5] = fmaf(p, xb.y, acc[5]);
            acc[6] = fmaf(p, xb.z, acc[6]);
            acc[7] = fmaf(p, xb.w, acc[7]);
        }
    }

    {   // iq-partials to LDS (stride 9)
        float* rb = &red[(iq * 128 + jj * 8 + h) * 9];
        #pragma unroll
        for (int d = 0; d < 8; ++d) rb[d] = acc[d];
        rb[8] = l;
    }
    __syncthreads();

    if (tid < 128) {                  // tid = r*8 + hh, r = out-row 0..15
        float o[9];
        #pragma unroll
        for (int d = 0; d < 9; ++d) o[d] = red[tid * 9 + d];
        #pragma unroll
        for (int q = 1; q < 4; ++q)
            #pragma unroll
            for (int d = 0; d < 9; ++d) o[d] += red[(q * 128 + tid) * 9 + d];

        const int hh = tid & 7;
        const int r = tid >> 3;
        const float rec = 1.0f / o[8];
        const float4 b0 = *reinterpret_cast<const float4*>(&bias[hh * 8]);
        const float4 b1 = *reinterpret_cast<const float4*>(&bias[hh * 8 + 4]);
        float4 o0, o1;
        o0.x = fmaxf(fmaf(o[0], rec, b0.x), 0.0f);
        o0.y = fmaxf(fmaf(o[1], rec, b0.y), 0.0f);
        o0.z = fmaxf(fmaf(o[2], rec, b0.z), 0.0f);
        o0.w = fmaxf(fmaf(o[3], rec, b0.w), 0.0f);
        o1.x = fmaxf(fmaf(o[4], rec, b1.x), 0.0f);
        o1.y = fmaxf(fmaf(o[5], rec, b1.y), 0.0f);
        o1.z = fmaxf(fmaf(o[6], rec, b1.z), 0.0f);
        o1.w = fmaxf(fmaf(o[7], rec, b1.w), 0.0f);
        float* xrow = &xs2[r * 68 + hh * 8];
        *reinterpret_cast<float4*>(xrow) = o0;
        *reinterpret_cast<float4*>(xrow + 4) = o1;
    }
    __syncthreads();

    // ---- proj(layer 2) on the 16 rows in xs2: all 512 threads ----
    // thread (r2 = tid>>5, c2 = tid&31) computes cols c2*2, c2*2+1.
    {
        const int r2 = tid >> 5, c2 = tid & 31;
        float a0 = 0.f, a1 = 0.f;
        #pragma unroll 4
        for (int k = 0; k < 64; ++k) {
            const float xv = xs2[r2 * 68 + k];
            const float2 w2 = *reinterpret_cast<const float2*>(&Wl2[k * 64 + c2 * 2]);
            a0 = fmaf(xv, w2.x, a0);
            a1 = fmaf(xv, w2.y, a1);
        }
        const int row2 = b * NN + j0 + r2;
        *reinterpret_cast<float2*>(&xp2[row2 * 64 + c2 * 2]) = make_float2(a0, a1);

        const int h2 = c2 >> 2, d0 = (c2 & 3) * 2;
        float sp = a0 * asrc2[h2 * 8 + d0] + a1 * asrc2[h2 * 8 + d0 + 1];
        float tp = a0 * adst2[h2 * 8 + d0] + a1 * adst2[h2 * 8 + d0 + 1];
        sp = sp + __shfl_xor(sp, 1);
        tp = tp + __shfl_xor(tp, 1);
        sp = sp + __shfl_xor(sp, 2);
        tp = tp + __shfl_xor(tp, 2);
        if ((tid & 3) == 0) {
            s2[row2 * 8 + h2] = sp;
            t2[row2 * 8 + h2] = tp;
            sl[r2 * 8 + h2] = sp;        // sl reused: dead since last barrier
        }
    }
    __syncthreads();
    if (tid < 8) {
        float mx = sl[tid];
        #pragma unroll
        for (int rr = 1; rr < 16; ++rr) mx = fmaxf(mx, sl[rr * 8 + tid]);
        pmax2[(b * 32 + blockIdx.x) * 8 + tid] = mx;
    }
}

// ---------------- Kernel 3: aggr(layer2) -> d_out ---------------------------
// R9 aggr core, epilogue writes relu(acc/l + bias2) to global.
__global__ __launch_bounds__(512) void gat_out(
    const float* __restrict__ xp,    // [B*N, 64]  layer-2 xp
    const float* __restrict__ s,     // [B*N, 8]
    const float* __restrict__ t,     // [B*N, 8]
    const float* __restrict__ pmax,  // [1024, 8]
    const int*   __restrict__ adj,   // [B, N, N]
    const float* __restrict__ bias,  // [64]
    float* __restrict__ outp)        // [B*N, 64]
{
    __shared__ float xpl[32 * 64];
    __shared__ float sl[32 * 8];
    __shared__ float ml[32 * 16];
    __shared__ float red[4 * 128 * 9];

    const int tid = threadIdx.x;
    const int b = blockIdx.y;
    const int j0 = blockIdx.x * 16;
    const int iq = tid >> 7;
    const int jj = (tid >> 3) & 15;
    const int h  = tid & 7;
    const int j  = j0 + jj;

    float sm = pmax[b * 256 + h];
    #pragma unroll
    for (int q = 1; q < 32; ++q) sm = fmaxf(sm, pmax[b * 256 + q * 8 + h]);

    const float tv = t[(b * NN + j) * 8 + h];
    const float m = lrelu(sm + tv);

    float acc[8] = {};
    float l = 0.f;

    float4 pa; float ps; int pmv;
    auto issue = [&](int i0) {
        pa = reinterpret_cast<const float4*>(&xp[(b * NN + i0) * 64])[tid];
        if (tid < 256) ps = s[(b * NN + i0) * 8 + tid];
        pmv = adj[(b * NN + i0 + (tid >> 4)) * NN + j0 + (tid & 15)];
    };
    issue(0);

    for (int c = 0; c < NN / 32; ++c) {
        const int i0 = c * 32;
        __syncthreads();
        reinterpret_cast<float4*>(xpl)[tid] = pa;
        if (tid < 256) sl[tid] = ps;
        ml[tid] = (pmv != 0 || (i0 + (tid >> 4)) == (j0 + (tid & 15))) ? 1.0f : 0.0f;
        if (c + 1 < NN / 32) issue(i0 + 32);
        __syncthreads();

        #pragma unroll
        for (int u = 0; u < 8; ++u) {
            const int ii = iq * 8 + u;
            const float e = lrelu(sl[ii * 8 + h] + tv);
            const float p = ml[ii * 16 + jj] * __expf(e - m);
            l += p;
            const float4* xr = reinterpret_cast<const float4*>(&xpl[ii * 64 + h * 8]);
            const float4 xa = xr[0], xb = xr[1];
            acc[0] = fmaf(p, xa.x, acc[0]);
            acc[1] = fmaf(p, xa.y, acc[1]);
            acc[2] = fmaf(p, xa.z, acc[2]);
            acc[3] = fmaf(p, xa.w, acc[3]);
            acc[4] = fmaf(p, xb.x, acc[4]);
            acc[5] = fmaf(p, xb.y, acc[5]);
            acc[6] = fmaf(p, xb.z, acc[6]);
            acc[7] = fmaf(p, xb.w, acc[7]);
        }
    }

    {
        float* rb = &red[(iq * 128 + jj * 8 + h) * 9];
        #pragma unroll
        for (int d = 0; d < 8; ++d) rb[d] = acc[d];
        rb[8] = l;
    }
    __syncthreads();

    if (tid < 128) {
        float o[9];
        #pragma unroll
        for (int d = 0; d < 9; ++d) o[d] = red[tid * 9 + d];
        #pragma unroll
        for (int q = 1; q < 4; ++q)
            #pragma unroll
            for (int d = 0; d < 9; ++d) o[d] += red[(q * 128 + tid) * 9 + d];

        const int hh = tid & 7;
        const float rec = 1.0f / o[8];
        const float4 b0 = *reinterpret_cast<const float4*>(&bias[hh * 8]);
        const float4 b1 = *reinterpret_cast<const float4*>(&bias[hh * 8 + 4]);
        float4 o0, o1;
        o0.x = fmaxf(fmaf(o[0], rec, b0.x), 0.0f);
        o0.y = fmaxf(fmaf(o[1], rec, b0.y), 0.0f);
        o0.z = fmaxf(fmaf(o[2], rec, b0.z), 0.0f);
        o0.w = fmaxf(fmaf(o[3], rec, b0.w), 0.0f);
        o1.x = fmaxf(fmaf(o[4], rec, b1.x), 0.0f);
        o1.y = fmaxf(fmaf(o[5], rec, b1.y), 0.0f);
        o1.z = fmaxf(fmaf(o[6], rec, b1.z), 0.0f);
        o1.w = fmaxf(fmaf(o[7], rec, b1.w), 0.0f);
        const int row = b * NN + j0 + (tid >> 3);
        float4* po = reinterpret_cast<float4*>(&outp[row * 64 + hh * 8]);
        po[0] = o0;
        po[1] = o1;
    }
}

} // namespace

extern "C" void kernel_launch(void* const* d_in, const int* in_sizes, int n_in,
                              void* d_out, int out_size, void* d_ws, size_t ws_size,
                              hipStream_t stream) {
    const float* n_in0  = (const float*)d_in[0];   // [B,N,64]
    const int*   adj    = (const int*)d_in[1];     // [B,N,N]
    const float* W1     = (const float*)d_in[2];
    const float* asrc1  = (const float*)d_in[3];
    const float* adst1  = (const float*)d_in[4];
    const float* b1     = (const float*)d_in[5];
    const float* W2     = (const float*)d_in[6];
    const float* asrc2  = (const float*)d_in[7];
    const float* adst2  = (const float*)d_in[8];
    const float* b2     = (const float*)d_in[9];

    float* ws = (float*)d_ws;
    float* xp1   = ws;                   // 1048576 floats
    float* s1    = xp1 + 1048576;        // 131072
    float* t1    = s1 + 131072;          // 131072
    float* pmax1 = t1 + 131072;          // 8192
    float* xp2   = pmax1 + 8192;         // 1048576
    float* s2    = xp2 + 1048576;        // 131072
    float* t2    = s2 + 131072;          // 131072
    float* pmax2 = t2 + 131072;          // 8192

    const dim3 gProj(NB * NN / 16);      // 1024 blocks
    const dim3 gAggr(NN / 16, NB);       // (32, 32)

    gat_proj<<<gProj, 256, 0, stream>>>(n_in0, W1, asrc1, adst1, xp1, s1, t1, pmax1);
    gat_mid<<<gAggr, 512, 0, stream>>>(xp1, s1, t1, pmax1, adj, b1,
                                       W2, asrc2, adst2, xp2, s2, t2, pmax2);
    gat_out<<<gAggr, 512, 0, stream>>>(xp2, s2, t2, pmax2, adj, b2, (float*)d_out);
}